// Round 16
// baseline (2542.722 us; speedup 1.0000x reference)
//
#include <hip/hip_runtime.h>
#include <hip/hip_cooperative_groups.h>
#include <math.h>

namespace cg = cooperative_groups;

#define N_NODES 131072
#define N_EDGES 2097152
#define DIM     64
#define BSUB    4096
#define NREL    3
#define NBASES  2
#define NCB     512     // coarse buckets (dst >> 8), 256 nodes each
#define CBSZ    8192    // edges per chist/cscatter block (256 blocks exactly)

typedef unsigned short u16;
typedef __attribute__((ext_vector_type(8))) short bf16x8;   // MFMA A/B frag (4 VGPRs)
typedef __attribute__((ext_vector_type(4))) float f32x4;    // MFMA C/D frag

__device__ __forceinline__ float bf2f(u16 x) {
    return __uint_as_float(((unsigned)x) << 16);
}
__device__ __forceinline__ u16 f2bf(float f) {
    unsigned u = __float_as_uint(f);
    unsigned r = (u + 0x7FFFu + ((u >> 16) & 1u)) >> 16;   // RNE
    return (u16)r;
}
__device__ __forceinline__ float4 bf4_to_f4(ushort4 u) {
    return make_float4(bf2f(u.x), bf2f(u.y), bf2f(u.z), bf2f(u.w));
}
__device__ __forceinline__ ushort4 f4_to_bf4(float4 v) {
    ushort4 o; o.x = f2bf(v.x); o.y = f2bf(v.y); o.z = f2bf(v.z); o.w = f2bf(v.w);
    return o;
}

// ================= R17/R21: MSD bucket sort replaces atomic CSR build ==========
// R2-R5: global returning atomics capped ~24 G/s chip-wide (invariant to
// padding/ILP/scope — memory-side execution). Sort uses LDS atomics per edge +
// ~131K global claim atomics (few µs).
// ================= R22: agg+gemm FUSION; h ping-pong. R22 tile body = measured
// optimum (occ 73%): R23 (fetch cut) no gain, R24 (pair ILP) regressed.
// ================= R25: ballot compaction + cvt/wpack fusion ====================
// ================= R26: cooperative mega-kernel =================================
// R15 accounting: 6 aggmm + preproc + head sum to ~380µs of ~565µs wall ->
// ~180µs is serialized launch gaps + ramp/drain tails across 13 launches.
// The 6 convs + head become ONE hipLaunchCooperativeKernel with grid.sync()
// between phases (harness-supported); each phase grid-strides its tiles.
// __threadfence() around grid.sync() for cross-XCD h visibility.

// ---------------- init: mark centers + zero coarse histogram + nld ----------------
__global__ void initmark_kernel(int* __restrict__ mark, int* __restrict__ chist,
                                int* __restrict__ nld) {
    int i = blockIdx.x * 256 + threadIdx.x;
    if (i < N_NODES) mark[i] = (i < BSUB) ? 1 : 0;
    if (i < NCB) chist[i] = 0;
    if (i == 0) *nld = 0;
}

// ---------------- pass A: coarse histogram (dst >> 8) ----------------
__global__ __launch_bounds__(256) void chist_kernel(const int* __restrict__ dst,
                                                    int* __restrict__ chist) {
    __shared__ int lh[NCB];
    int tid = threadIdx.x;
    lh[tid] = 0; lh[tid + 256] = 0;
    __syncthreads();
    int base = blockIdx.x * CBSZ;
#pragma unroll
    for (int j = 0; j < CBSZ / 1024; j++) {          // 8 iters, 4 edges/thread
        int4 d4 = *(const int4*)(dst + base + j * 1024 + tid * 4);
        atomicAdd(&lh[d4.x >> 8], 1);
        atomicAdd(&lh[d4.y >> 8], 1);
        atomicAdd(&lh[d4.z >> 8], 1);
        atomicAdd(&lh[d4.w >> 8], 1);
    }
    __syncthreads();
    atomicAdd(&chist[tid], lh[tid]);                 // non-returning
    atomicAdd(&chist[tid + 256], lh[tid + 256]);
}

// ---------------- coarse scan: chist -> cbase (excl) + ccur copy ----------------
__global__ void cscan_kernel(const int* __restrict__ chist, int* __restrict__ cbase,
                             int* __restrict__ ccur, int* __restrict__ offs) {
    __shared__ int s[NCB];
    int tid = threadIdx.x;        // 512 threads
    int v = chist[tid];
    s[tid] = v;
    __syncthreads();
    int val = v;
    for (int off = 1; off < NCB; off <<= 1) {
        int tmp = (tid >= off) ? s[tid - off] : 0;
        __syncthreads();
        val += tmp;
        s[tid] = val;
        __syncthreads();
    }
    cbase[tid] = val - v;
    ccur[tid] = val - v;
    if (tid == 0) offs[N_NODES] = N_EDGES;
}

// ---------------- pass B: coarse scatter (full payload) + frontier mark --------
// 256 blocks x 512 threads (8 waves/CU); per-thread 4-edge ILP, 4 iterations.
__global__ __launch_bounds__(512) void cscatter_kernel(
    const int* __restrict__ src, const int* __restrict__ dst,
    const int* __restrict__ et, const float* __restrict__ m1,
    const float* __restrict__ m2, int* __restrict__ ccur,
    int4* __restrict__ tmp, int* __restrict__ mark) {
    __shared__ int lh[NCB];
    __shared__ int lbase[NCB];
    int tid = threadIdx.x;        // 0..511
    lh[tid] = 0;
    __syncthreads();
    int e0b = blockIdx.x * CBSZ;
#pragma unroll
    for (int j = 0; j < CBSZ / 2048; j++) {          // 4 iters
        int4 d4 = *(const int4*)(dst + e0b + j * 2048 + tid * 4);
        atomicAdd(&lh[d4.x >> 8], 1);
        atomicAdd(&lh[d4.y >> 8], 1);
        atomicAdd(&lh[d4.z >> 8], 1);
        atomicAdd(&lh[d4.w >> 8], 1);
    }
    __syncthreads();
    int c = lh[tid];
    lbase[tid] = c ? atomicAdd(&ccur[tid], c) : 0;   // returning, 512/block
    lh[tid] = 0;                 // reuse as local cursor (own-slot only)
    __syncthreads();
#pragma unroll
    for (int j = 0; j < CBSZ / 2048; j++) {
        int e0 = e0b + j * 2048 + tid * 4;
        int4  d4 = *(const int4*)(dst + e0);
        int4  s4 = *(const int4*)(src + e0);
        int4  t4 = *(const int4*)(et + e0);
        float4 a4 = *(const float4*)(m1 + e0);
        float4 b4 = *(const float4*)(m2 + e0);
#pragma unroll
        for (int k = 0; k < 4; k++) {
            int d = (&d4.x)[k];
            int s = (&s4.x)[k];
            int b = d >> 8;
            int r = atomicAdd(&lh[b], 1);            // LDS returning
            int4 v;
            v.x = s | ((&t4.x)[k] << 20);
            v.y = __float_as_int((&a4.x)[k]);
            v.z = __float_as_int((&b4.x)[k]);
            v.w = d;
            tmp[lbase[b] + r] = v;
            if (d < BSUB) mark[s] = 1;               // benign race: all write 1
        }
    }
}

// ---------------- pass C: fine scatter within coarse bucket + offs write -------
// 512 blocks (2/CU), one per bucket (256 nodes, ~4096 edges, 64 KB csr region).
__global__ __launch_bounds__(256) void fscatter_kernel(
    const int4* __restrict__ tmp, const int* __restrict__ cbase,
    const int* __restrict__ chist, int* __restrict__ offs,
    int4* __restrict__ csr) {
    __shared__ int lh[256];
    __shared__ int lpre[256];
    __shared__ int s[256];
    int b = blockIdx.x;
    int tid = threadIdx.x;
    int base = cbase[b], cnt = chist[b];
    lh[tid] = 0;
    __syncthreads();
    int i = 0;
    for (; i + 1024 <= cnt; i += 1024) {
        int4 v0 = tmp[base + i + tid * 4 + 0];
        int4 v1 = tmp[base + i + tid * 4 + 1];
        int4 v2 = tmp[base + i + tid * 4 + 2];
        int4 v3 = tmp[base + i + tid * 4 + 3];
        atomicAdd(&lh[v0.w & 255], 1);
        atomicAdd(&lh[v1.w & 255], 1);
        atomicAdd(&lh[v2.w & 255], 1);
        atomicAdd(&lh[v3.w & 255], 1);
    }
    for (int k = i + tid; k < cnt; k += 256)
        atomicAdd(&lh[tmp[base + k].w & 255], 1);
    __syncthreads();
    // exclusive scan of 256 bins
    int v = lh[tid];
    s[tid] = v;
    __syncthreads();
    int val = v;
    for (int off = 1; off < 256; off <<= 1) {
        int tq = (tid >= off) ? s[tid - off] : 0;
        __syncthreads();
        val += tq;
        s[tid] = val;
        __syncthreads();
    }
    int ex = val - v;
    lpre[tid] = ex;
    offs[b * 256 + tid] = base + ex;     // offs for this bucket's 256 nodes
    lh[tid] = 0;                          // reuse as cursors
    __syncthreads();
    i = 0;
    for (; i + 1024 <= cnt; i += 1024) {
        int4 v0 = tmp[base + i + tid * 4 + 0];
        int4 v1 = tmp[base + i + tid * 4 + 1];
        int4 v2 = tmp[base + i + tid * 4 + 2];
        int4 v3 = tmp[base + i + tid * 4 + 3];
        int k0 = v0.w & 255; int r0 = atomicAdd(&lh[k0], 1); csr[base + lpre[k0] + r0] = v0;
        int k1 = v1.w & 255; int r1 = atomicAdd(&lh[k1], 1); csr[base + lpre[k1] + r1] = v1;
        int k2 = v2.w & 255; int r2 = atomicAdd(&lh[k2], 1); csr[base + lpre[k2] + r2] = v2;
        int k3 = v3.w & 255; int r3 = atomicAdd(&lh[k3], 1); csr[base + lpre[k3] + r3] = v3;
    }
    for (int kk = i + tid; kk < cnt; kk += 256) {
        int4 vv = tmp[base + kk];
        int k = vv.w & 255;
        int r = atomicAdd(&lh[k], 1);
        csr[base + lpre[k] + r] = vv;                // .w carries dst (agg ignores)
    }
}

// ---------------- R25: one-kernel mark compaction (ballot + wave atomic) -------
__global__ void marklist_kernel(const int* __restrict__ mark, int* __restrict__ list,
                                int* __restrict__ nld) {
    int i = blockIdx.x * 256 + threadIdx.x;
    int lane = threadIdx.x & 63;
    int m = mark[i];
    unsigned long long b = __ballot(m != 0);
    int cnt = __popcll(b);
    int base = 0;
    if (lane == 0 && cnt) base = atomicAdd(nld, cnt);
    base = __shfl(base, 0, 64);
    if (m) list[base + __popcll(b & ((1ULL << lane) - 1ULL))] = i;
}

// ---------------- R25 fused: x -> bf16 convert  +  weight packing --------------
__global__ void cvtpack_kernel(const float4* __restrict__ x, ushort4* __restrict__ hb,
                               const float* __restrict__ lV, const float* __restrict__ lW,
                               const float* __restrict__ gV, const float* __restrict__ gW,
                               u16* __restrict__ wfrag) {
    if (blockIdx.x < 8192) {
        int i = blockIdx.x * 256 + threadIdx.x;
        hb[i] = f4_to_bf4(x[i]);
        return;
    }
    int idx = (blockIdx.x - 8192) * 256 + threadIdx.x;   // 6*4*6*64 = 9216
    if (idx >= 6 * 4 * 6 * 64) return;
    int lane = idx & 63;
    int kidx = (idx >> 6) % 6;
    int nt   = (idx >> 6) / 6 % 4;
    int c    = idx / (64 * 6 * 4);      // conv 0..5
    int layer = c >> 1;
    bool isglobal = c & 1;
    const float* V = isglobal ? gV : lV;
    const float* W = isglobal ? gW : lW;
    int n = nt * 16 + (lane & 15);
    int kbase = kidx * 32 + (lane >> 4) * 8;
    u16 vals[8];
#pragma unroll
    for (int j = 0; j < 8; j++) {
        int r = kbase + j;      // 0..191
        float val;
        if (r < NBASES * DIM) {
            int b = r >> 6, d = r & 63;
            val = V[((layer * NBASES + b) * DIM + d) * DIM + n];
        } else {
            int d = r - NBASES * DIM;
            val = W[(layer * DIM + d) * DIM + n];
        }
        vals[j] = f2bf(val);
    }
    ushort4* o = (ushort4*)(wfrag + (size_t)idx * 8);
    o[0] = make_ushort4(vals[0], vals[1], vals[2], vals[3]);
    o[1] = make_ushort4(vals[4], vals[5], vals[6], vals[7]);
}

// ---------------- R26 cooperative mega-kernel: 6 convs + head ------------------
// Phase p (0..5): layer p>>1, global if p&1. Each phase grid-strides over its
// 16-node tiles using the EXACT R22 tile body (agg 4 nodes/wave -> LDS t_tile
// -> 16x16 MFMA gemm -> act -> hout/subg). grid.sync() + __threadfence()
// between phases (h ping-pong). Final phase: MLP head.
__global__ __launch_bounds__(256, 8) void mega_kernel(
    ushort4* __restrict__ h0, ushort4* __restrict__ h1,
    const int4* __restrict__ csr, const int* __restrict__ offs,
    const float* __restrict__ lC, const float* __restrict__ gC,
    const u16* __restrict__ wfrag, const float* __restrict__ lB,
    const float* __restrict__ gB, const int* __restrict__ list,
    const int* __restrict__ nld, float* __restrict__ subg,
    const float* __restrict__ w1, const float* __restrict__ b1,
    const float* __restrict__ w2, const float* __restrict__ b2,
    float* __restrict__ out) {
    cg::grid_group gg = cg::this_grid();
    __shared__ int4 lmeta[4][64];
    __shared__ alignas(16) ushort4 t_tile[16][34];   // 16 rows x 256B, +16B pad
    __shared__ float srow[4][192];
    int lane = threadIdx.x & 63;
    int wid  = threadIdx.x >> 6;
    int q  = lane >> 4;     // quarter 0..3
    int ql = lane & 15;     // lane within quarter
    const int convfrag = 4 * 6 * 64 * 8;
    ushort4* hbuf[2] = {h0, h1};
    int cur = 0;

    for (int phase = 0; phase < 6; phase++) {
        int layer = phase >> 1;
        int isg   = phase & 1;
        const float* Cc = (isg ? gC : lC) + layer * NREL * NBASES;
        float Ca0 = Cc[0], Cb0 = Cc[1], Ca1 = Cc[2], Cb1 = Cc[3], Ca2 = Cc[4], Cb2 = Cc[5];
        const u16* wf = wfrag + (size_t)phase * convfrag;
        const float* bias = (isg ? gB : lB) + layer * 64;
        const ushort4* hin = hbuf[cur];
        u16* hout = (u16*)hbuf[cur ^ 1];
        const int* ll = (phase == 4) ? list : nullptr;   // layer-2 local pruned
        int nN = (phase == 5) ? BSUB : N_NODES;
        int nld_v = ll ? *nld : 0;
        int lim = ll ? nld_v : nN;
        int ntiles = (lim + 15) >> 4;
        float* sg = isg ? subg : nullptr;
        int sgoff = layer * 64;

        for (int tile = blockIdx.x; tile < ntiles; tile += gridDim.x) {
            int slot0 = tile << 4;
            // ---- agg phase: 4 nodes per wave, sequential (R22 body) ----
            for (int i = 0; i < 4; i++) {
                int slot = slot0 + (wid << 2) + i;
                int n = -1;
                if (ll) { if (slot < nld_v) n = ll[slot]; }
                else if (slot < nN) n = slot;
                float4 a0 = make_float4(0.f, 0.f, 0.f, 0.f);
                float4 a1 = make_float4(0.f, 0.f, 0.f, 0.f);
                if (n >= 0) {
                    int beg = offs[n], end = offs[n + 1];
                    for (int base = beg; base < end; base += 64) {
                        int cnt = min(64, end - base);
                        int pp = 0; float c0 = 0.f, c1 = 0.f;
                        if (lane < cnt) {
                            int4 meta = csr[base + lane];
                            int et = ((unsigned)meta.x) >> 20;
                            float m = __int_as_float(isg ? meta.z : meta.y);
                            float ca = et == 0 ? Ca0 : (et == 1 ? Ca1 : Ca2);
                            float cb = et == 0 ? Cb0 : (et == 1 ? Cb1 : Cb2);
                            pp = (meta.x & 0xFFFFF) << 4;    // pre-scaled hb row base
                            c0 = m * ca;
                            c1 = m * cb;
                        }
                        lmeta[wid][lane] = make_int4(pp, __float_as_int(c0),
                                                     __float_as_int(c1), 0);
                        for (int j = 0; j < cnt; j += 16) {
#pragma unroll
                            for (int s = 0; s < 4; s++) {
                                int4 md = lmeta[wid][j + (s << 2) + q];
                                ushort4 rv = hin[md.x + ql];
                                float4 v = bf4_to_f4(rv);
                                float e0 = __int_as_float(md.y);
                                float e1 = __int_as_float(md.z);
                                a0.x = fmaf(e0, v.x, a0.x); a0.y = fmaf(e0, v.y, a0.y);
                                a0.z = fmaf(e0, v.z, a0.z); a0.w = fmaf(e0, v.w, a0.w);
                                a1.x = fmaf(e1, v.x, a1.x); a1.y = fmaf(e1, v.y, a1.y);
                                a1.z = fmaf(e1, v.z, a1.z); a1.w = fmaf(e1, v.w, a1.w);
                            }
                        }
                    }
#pragma unroll
                    for (int off = 16; off < 64; off <<= 1) {
                        a0.x += __shfl_xor(a0.x, off, 64); a0.y += __shfl_xor(a0.y, off, 64);
                        a0.z += __shfl_xor(a0.z, off, 64); a0.w += __shfl_xor(a0.w, off, 64);
                        a1.x += __shfl_xor(a1.x, off, 64); a1.y += __shfl_xor(a1.y, off, 64);
                        a1.z += __shfl_xor(a1.z, off, 64); a1.w += __shfl_xor(a1.w, off, 64);
                    }
                    if (q < 2)
                        t_tile[(wid << 2) + i][(q << 4) + ql] = f4_to_bf4(q == 0 ? a0 : a1);
                }
            }
            __syncthreads();
            // ---- gemm phase: wave w -> 16 rows x cols [w*16, w*16+16) ----
            int myslot = slot0 + ql;
            int rowA = ll ? ll[min(myslot, nld_v - 1)] : min(myslot, nN - 1);
            const u16* hrow = (const u16*)hin + (size_t)rowA * 64;
            const u16* trow = (const u16*)&t_tile[ql][0];
            f32x4 acc = {0.f, 0.f, 0.f, 0.f};
#pragma unroll
            for (int kidx = 0; kidx < 6; kidx++) {
                bf16x8 a = (kidx < 4)
                    ? *(const bf16x8*)(trow + kidx * 32 + q * 8)
                    : *(const bf16x8*)(hrow + (kidx - 4) * 32 + q * 8);
                bf16x8 b = *(const bf16x8*)(wf + ((size_t)(wid * 6 + kidx) * 64 + lane) * 8);
                acc = __builtin_amdgcn_mfma_f32_16x16x32_bf16(a, b, acc, 0, 0, 0);
            }
            int col = wid * 16 + ql;
            float bcol = bias[col];
#pragma unroll
            for (int r = 0; r < 4; r++) {
                int cslot = slot0 + q * 4 + r;
                if (ll && cslot >= nld_v) continue;
                int row = ll ? __shfl(rowA, q * 4 + r, 64) : cslot;
                float xv = acc[r] + bcol;
                float v = isg ? (xv > 0.f ? xv : 0.01f * xv)
                              : (xv > 0.f ? xv : expm1f(xv));
                hout[(size_t)row * 64 + col] = f2bf(v);
                if (sg && row < BSUB)
                    sg[(size_t)row * 192 + sgoff + col] = v;
            }
            __syncthreads();   // t_tile reused by next tile's agg
        }
        cur ^= 1;
        __threadfence();       // make h/subg visible across XCDs
        gg.sync();
        __threadfence();       // acquire side
    }

    // ---- head phase: [4096,192] -> relu 128 -> sigmoid 1 ----
    for (int t = blockIdx.x; t < BSUB / 4; t += gridDim.x) {
        int row = t * 4 + wid;
        const float* sr = subg + (size_t)row * 192;
        srow[wid][lane] = sr[lane];
        srow[wid][64 + lane] = sr[64 + lane];
        srow[wid][128 + lane] = sr[128 + lane];
        __syncthreads();
        float acc1 = b1[lane], acc2 = b1[64 + lane];
        const float* w1a = w1 + lane * 192;
        const float* w1b = w1 + (64 + lane) * 192;
        for (int k = 0; k < 192; k++) {
            float s = srow[wid][k];
            acc1 = fmaf(s, w1a[k], acc1);
            acc2 = fmaf(s, w1b[k], acc2);
        }
        acc1 = fmaxf(acc1, 0.f);
        acc2 = fmaxf(acc2, 0.f);
        float part = acc1 * w2[lane] + acc2 * w2[64 + lane];
        for (int off = 32; off; off >>= 1) part += __shfl_down(part, off, 64);
        if (lane == 0) out[row] = 1.f / (1.f + expf(-(part + b2[0])));
        __syncthreads();
    }
}

extern "C" void kernel_launch(void* const* d_in, const int* in_sizes, int n_in,
                              void* d_out, int out_size, void* d_ws, size_t ws_size,
                              hipStream_t stream) {
    const float* x     = (const float*)d_in[0];
    const int*   src   = (const int*)d_in[1];
    const int*   dst   = (const int*)d_in[2];
    const int*   etype = (const int*)d_in[3];
    const float* mask  = (const float*)d_in[4];
    const float* mask2 = (const float*)d_in[5];
    const float* lV = (const float*)d_in[6];
    const float* lC = (const float*)d_in[7];
    const float* lW = (const float*)d_in[8];
    const float* lB = (const float*)d_in[9];
    const float* gV = (const float*)d_in[10];
    const float* gC = (const float*)d_in[11];
    const float* gW = (const float*)d_in[12];
    const float* gB = (const float*)d_in[13];
    const float* w1 = (const float*)d_in[14];
    const float* b1 = (const float*)d_in[15];
    const float* w2 = (const float*)d_in[16];
    const float* b2 = (const float*)d_in[17];
    float* out = (float*)d_out;

    // workspace carve-up
    char* ws = (char*)d_ws;
    size_t off = 0;
    auto alloc = [&](size_t bytes) {
        void* p = ws + off;
        off += (bytes + 255) & ~(size_t)255;
        return p;
    };
    ushort4* h0   = (ushort4*)alloc((size_t)N_NODES * 64 * 2);     // bf16 [N,64]
    ushort4* h1   = (ushort4*)alloc((size_t)N_NODES * 64 * 2);     // ping-pong
    int4*  csr    = (int4*)alloc((size_t)N_EDGES * 16);
    int*   offs   = (int*)alloc((size_t)(N_NODES + 1) * 4);
    int*   chist  = (int*)alloc(NCB * 4);
    int*   cbase  = (int*)alloc(NCB * 4);
    int*   ccur   = (int*)alloc(NCB * 4);
    int*   mark   = (int*)alloc((size_t)N_NODES * 4);
    int*   list   = (int*)alloc((size_t)N_NODES * 4);
    int*   nld    = (int*)alloc(256);
    u16*   wfrag  = (u16*)alloc((size_t)6 * 4 * 6 * 64 * 8 * 2);
    float* subg   = (float*)alloc((size_t)BSUB * 192 * 4);
    // tmp (coarse-sorted payload, 32 MB) aliases h0+h1 (contiguous, dead until
    // cvt/conv which run after fscatter).
    int4*  tmp    = (int4*)h0;

    // ---- graph preprocessing (R17/R21 sort pipeline, R25 launch-reduced) ----
    initmark_kernel<<<N_NODES / 256, 256, 0, stream>>>(mark, chist, nld);
    chist_kernel<<<N_EDGES / CBSZ, 256, 0, stream>>>(dst, chist);
    cscan_kernel<<<1, NCB, 0, stream>>>(chist, cbase, ccur, offs);
    cscatter_kernel<<<N_EDGES / CBSZ, 512, 0, stream>>>(src, dst, etype, mask, mask2,
                                                        ccur, tmp, mark);
    fscatter_kernel<<<NCB, 256, 0, stream>>>(tmp, cbase, chist, offs, csr);
    marklist_kernel<<<N_NODES / 256, 256, 0, stream>>>(mark, list, nld);
    // cvt (h0 aliases tmp -> AFTER fscatter) + wpack fused
    cvtpack_kernel<<<8192 + 36, 256, 0, stream>>>((const float4*)x, h0,
                                                  lV, lW, gV, gW, wfrag);

    // ---- R26: one cooperative launch for 6 convs + head ----
    static int bpc = 0;
    if (bpc == 0) {
        hipOccupancyMaxActiveBlocksPerMultiprocessor(&bpc, mega_kernel, 256, 0);
        if (bpc < 1) bpc = 1;
        if (bpc > 8) bpc = 8;
    }
    int mgrid = bpc * 256;           // blocks co-resident on 256 CUs
    if (mgrid > 8192) mgrid = 8192;
    void* kargs[] = {(void*)&h0, (void*)&h1, (void*)&csr, (void*)&offs,
                     (void*)&lC, (void*)&gC, (void*)&wfrag, (void*)&lB,
                     (void*)&gB, (void*)&list, (void*)&nld, (void*)&subg,
                     (void*)&w1, (void*)&b1, (void*)&w2, (void*)&b2,
                     (void*)&out};
    hipLaunchCooperativeKernel(mega_kernel, dim3(mgrid), dim3(256),
                               kargs, 0, stream);
}